// Round 1
// baseline (796.753 us; speedup 1.0000x reference)
//
#include <hip/hip_runtime.h>

#define NB 32
#define CCH 64
#define HH 96
#define WWID 96
#define HWP (HH*WWID)   // 9216
#define K7 448

// ---------------------------------------------------------------------------
// ws layout (floats):
//   t2p : [32][16][64][64]  partial Gram sums       = 2,097,152
//   t5  : [32][64][64]      p5 * t2 / 96            =   131,072
//   t8  : [32][448][64]     p8^T @ t5 / sqrt(448)   =   917,504
//   t6  : [32][9216]        sum_c t4*p6             =   294,912
//   t9  : [32][64]          <t3, t6>/96             =     2,048
// total ≈ 13.8 MB
// ---------------------------------------------------------------------------
#define OFF_T5 2097152
#define OFF_T8 2228224
#define OFF_T6 3145728
#define OFF_T9 3440640

// t1[n,c,h,w] = x[n,c,(h-1)%96,(w+1)%96]
__device__ __forceinline__ int roll_idx(int i) {
    int h = i / WWID;
    int w = i - h * WWID;
    return ((h + HH - 1) % HH) * WWID + ((w + 1) % WWID);
}

// ---------------------------------------------------------------------------
// Kernel A: t2 partials.  t2[n,c,d] = sum_i x[n,c,i] * t1[n,d,i]   (K split 16)
// grid: 512 blocks (n*16+slice), 256 threads, 4x4 register tile.
// ---------------------------------------------------------------------------
__global__ __launch_bounds__(256) void k_t2(const float* __restrict__ x,
                                            float* __restrict__ t2p) {
    int blk = blockIdx.x;
    int n = blk >> 4, sl = blk & 15;
    int k0 = sl * (HWP / 16);          // 576 per slice
    __shared__ float ash[32][68];      // kk-major, +4 pad (4-way write conflict ok)
    __shared__ float bsh[32][68];
    int t = threadIdx.x;
    int c0 = (t >> 4) * 4;
    int d0 = (t & 15) * 4;
    float acc[4][4] = {};
    const float* xa = x + (size_t)n * CCH * HWP;

    for (int kc = 0; kc < 576; kc += 32) {
        __syncthreads();
#pragma unroll
        for (int i = 0; i < 8; i++) {
            int idx = i * 256 + t;         // 2048 elems per matrix
            int c = idx >> 5, kk = idx & 31;
            int gi = k0 + kc + kk;
            ash[kk][c] = xa[c * HWP + gi];
            bsh[kk][c] = xa[c * HWP + roll_idx(gi)];
        }
        __syncthreads();
#pragma unroll
        for (int kk = 0; kk < 32; kk++) {
            float4 va = *(const float4*)&ash[kk][c0];
            float4 vb = *(const float4*)&bsh[kk][d0];
            float av[4] = {va.x, va.y, va.z, va.w};
            float bv[4] = {vb.x, vb.y, vb.z, vb.w};
#pragma unroll
            for (int i = 0; i < 4; i++)
#pragma unroll
                for (int j = 0; j < 4; j++)
                    acc[i][j] = fmaf(av[i], bv[j], acc[i][j]);
        }
    }
    float* o = t2p + (((size_t)n * 16 + sl) * 64 + c0) * 64 + d0;
#pragma unroll
    for (int i = 0; i < 4; i++) {
        float4 v = {acc[i][0], acc[i][1], acc[i][2], acc[i][3]};
        *(float4*)(o + i * 64) = v;
    }
}

// ---------------------------------------------------------------------------
// Kernel B1: t5[n,b,c] = p5[b,c] * (sum_slices t2p) / 96
// ---------------------------------------------------------------------------
__global__ __launch_bounds__(256) void k_t5(const float* __restrict__ t2p,
                                            const float* __restrict__ p5,
                                            float* __restrict__ t5) {
    int idx = blockIdx.x * 256 + threadIdx.x;   // [0, 32*4096)
    int n = idx >> 12, rc = idx & 4095;
    float s = 0.f;
#pragma unroll
    for (int sl = 0; sl < 16; sl++)
        s += t2p[((size_t)n * 16 + sl) * 4096 + rc];
    t5[idx] = s * p5[rc] * (1.0f / 96.0f);
}

// ---------------------------------------------------------------------------
// Kernel B2: t8[n,k,c] = (1/sqrt(448)) * sum_b t5[n,b,c] * p8[b,k]
// grid (112, 32); per-wave k is uniform -> p8 broadcast, t5 coalesced.
// ---------------------------------------------------------------------------
__global__ __launch_bounds__(256) void k_t8(const float* __restrict__ t5,
                                            const float* __restrict__ p8,
                                            float* __restrict__ t8) {
    int n = blockIdx.y;
    int idx = blockIdx.x * 256 + threadIdx.x;   // [0, 448*64)
    int k = idx >> 6, c = idx & 63;
    const float* t5n = t5 + (size_t)n * 4096;
    float s = 0.f;
#pragma unroll 8
    for (int b = 0; b < 64; b++)
        s += t5n[b * 64 + c] * p8[b * K7 + k];
    t8[((size_t)n * K7 + k) * 64 + c] = s * 0.04724555912f;  // 1/sqrt(448)
}

// ---------------------------------------------------------------------------
// Kernel C1: t6[n,h,w] = sum_c p6[c] * dwconv3x3_d2(t1)[n,c,h,w]
// zero-pad(2) applied to t1; t1 itself wraps (roll of x).
// ---------------------------------------------------------------------------
__global__ __launch_bounds__(256) void k_t6(const float* __restrict__ x,
                                            const float* __restrict__ w4,
                                            const float* __restrict__ p6,
                                            float* __restrict__ t6) {
    int n = blockIdx.y;
    int pix = blockIdx.x * 256 + threadIdx.x;   // < 9216
    int h = pix / WWID, w = pix - h * WWID;
    const float* xn = x + (size_t)n * CCH * HWP;
    float acc = 0.f;
    for (int c = 0; c < CCH; c++) {
        const float* wc = w4 + c * 9;
        const float* xc = xn + c * HWP;
        float a = 0.f;
#pragma unroll
        for (int kh = 0; kh < 3; kh++) {
            int hh = h + (kh - 1) * 2;
            if (hh < 0 || hh >= HH) continue;
            int srow = ((hh + HH - 1) % HH) * WWID;
#pragma unroll
            for (int kw = 0; kw < 3; kw++) {
                int ww = w + (kw - 1) * 2;
                if (ww < 0 || ww >= WWID) continue;
                a = fmaf(wc[kh * 3 + kw], xc[srow + (ww + 1) % WWID], a);
            }
        }
        acc = fmaf(p6[c], a, acc);
    }
    t6[(size_t)n * HWP + pix] = acc;
}

// ---------------------------------------------------------------------------
// Kernel C2: t9[n,c] = (1/96) * sum_pix dwconv5x5_d1(t1)[n,c,pix] * t6[n,pix]
// t3 is never materialized. grid (64, 32), block reduce.
// ---------------------------------------------------------------------------
__global__ __launch_bounds__(256) void k_t9(const float* __restrict__ x,
                                            const float* __restrict__ w3,
                                            const float* __restrict__ t6,
                                            float* __restrict__ t9) {
    int n = blockIdx.y, c = blockIdx.x;
    const float* xc = x + ((size_t)n * CCH + c) * HWP;
    const float* t6n = t6 + (size_t)n * HWP;
    float wv[25];
#pragma unroll
    for (int i = 0; i < 25; i++) wv[i] = w3[c * 25 + i];
    float acc = 0.f;
    for (int pix = threadIdx.x; pix < HWP; pix += 256) {
        int h = pix / WWID, w = pix - h * WWID;
        float conv = 0.f;
#pragma unroll
        for (int kh = 0; kh < 5; kh++) {
            int hh = h + kh - 2;
            if (hh < 0 || hh >= HH) continue;
            int srow = ((hh + HH - 1) % HH) * WWID;
#pragma unroll
            for (int kw = 0; kw < 5; kw++) {
                int ww = w + kw - 2;
                if (ww < 0 || ww >= WWID) continue;
                conv = fmaf(wv[kh * 5 + kw], xc[srow + (ww + 1) % WWID], conv);
            }
        }
        acc = fmaf(conv, t6n[pix], acc);
    }
#pragma unroll
    for (int off = 32; off > 0; off >>= 1) acc += __shfl_down(acc, off, 64);
    __shared__ float red[4];
    if ((threadIdx.x & 63) == 0) red[threadIdx.x >> 6] = acc;
    __syncthreads();
    if (threadIdx.x == 0)
        t9[n * 64 + c] = (red[0] + red[1] + red[2] + red[3]) * (1.0f / 96.0f);
}

// ---------------------------------------------------------------------------
// Kernel D: out[n,c,h,w] = t9[n,c] + sum_{c7,kk} t8[n,c7*7+kk,c] * xpad[n,c7,h,w+2kk-6]
// Block = (n, h-pair). Wave <-> 16-channel group (uniform -> W via s_load).
// Lane: row = lane>>5, covers w0..w0+2 (stride-3 -> conflict-free LDS).
// acc tile 16c x 3w = 48 regs; VALU-bound by design.
// ---------------------------------------------------------------------------
__global__ __launch_bounds__(256, 2) void k_out(const float* __restrict__ x,
                                                const float* __restrict__ t8,
                                                const float* __restrict__ t9,
                                                float* __restrict__ out) {
    int n = blockIdx.y;
    int h0 = blockIdx.x * 2;
    __shared__ float xsh[2][CCH][112];   // [row][c7][6-pad | 96 | 10-pad]
    int t = threadIdx.x;
    const float* xn = x + (size_t)n * CCH * HWP;

    // zero the pads: 16 entries per (row,c7)
    for (int idx = t; idx < 2 * CCH * 16; idx += 256) {
        int r = idx >> 10;                  // /(64*16)
        int rem = idx & 1023;
        int c7 = rem >> 4, p = rem & 15;
        xsh[r][c7][p < 6 ? p : 96 + p] = 0.f;
    }
    // fill interior
    for (int idx = t; idx < 2 * CCH * WWID; idx += 256) {
        int r = idx / (CCH * WWID);
        int rem = idx - r * (CCH * WWID);
        int c7 = rem / WWID;
        int w = rem - c7 * WWID;
        xsh[r][c7][6 + w] = xn[c7 * HWP + (h0 + r) * WWID + w];
    }
    __syncthreads();

    int wave = __builtin_amdgcn_readfirstlane(t >> 6);   // 0..3, uniform
    int lane = t & 63;
    int row = lane >> 5;          // 0..1
    int wl = lane & 31;
    int w0 = wl * 3;
    int c0 = wave * 16;
    float acc[16][3] = {};
    const float* t8n = t8 + (size_t)n * K7 * 64 + c0;

    for (int c7 = 0; c7 < CCH; c7++) {
        float xv[15];
        const float* xc = &xsh[row][c7][w0];
#pragma unroll
        for (int i = 0; i < 15; i++) xv[i] = xc[i];
#pragma unroll
        for (int kk = 0; kk < 7; kk++) {
            const float* wr = t8n + (c7 * 7 + kk) * 64;  // uniform addr -> s_load
            float wv[16];
#pragma unroll
            for (int i = 0; i < 16; i++) wv[i] = wr[i];
#pragma unroll
            for (int i = 0; i < 16; i++) {
                acc[i][0] = fmaf(wv[i], xv[2 * kk],     acc[i][0]);
                acc[i][1] = fmaf(wv[i], xv[2 * kk + 1], acc[i][1]);
                acc[i][2] = fmaf(wv[i], xv[2 * kk + 2], acc[i][2]);
            }
        }
    }

    const float* t9n = t9 + n * 64 + c0;   // uniform
    float* on = out + (size_t)n * CCH * HWP + (size_t)(h0 + row) * WWID + w0;
#pragma unroll
    for (int i = 0; i < 16; i++) {
        float tv = t9n[i];
        float* orow = on + (size_t)(c0 + i) * HWP;
        orow[0] = acc[i][0] + tv;
        orow[1] = acc[i][1] + tv;
        orow[2] = acc[i][2] + tv;
    }
}

// ---------------------------------------------------------------------------
extern "C" void kernel_launch(void* const* d_in, const int* in_sizes, int n_in,
                              void* d_out, int out_size, void* d_ws, size_t ws_size,
                              hipStream_t stream) {
    const float* x  = (const float*)d_in[0];
    const float* w3 = (const float*)d_in[1];
    const float* w4 = (const float*)d_in[2];
    const float* p5 = (const float*)d_in[3];
    const float* p6 = (const float*)d_in[4];
    const float* p8 = (const float*)d_in[5];
    float* out = (float*)d_out;
    float* ws  = (float*)d_ws;

    float* t2p = ws;
    float* t5  = ws + OFF_T5;
    float* t8  = ws + OFF_T8;
    float* t6  = ws + OFF_T6;
    float* t9  = ws + OFF_T9;

    k_t2<<<512, 256, 0, stream>>>(x, t2p);
    k_t5<<<512, 256, 0, stream>>>(t2p, p5, t5);
    k_t8<<<dim3(112, 32), 256, 0, stream>>>(t5, p8, t8);
    k_t6<<<dim3(36, 32), 256, 0, stream>>>(x, w4, p6, t6);
    k_t9<<<dim3(64, 32), 256, 0, stream>>>(x, w3, t6, t9);
    k_out<<<dim3(48, 32), 256, 0, stream>>>(x, t8, t9, out);
}

// Round 2
// 295.354 us; speedup vs baseline: 2.6976x; 2.6976x over previous
//
#include <hip/hip_runtime.h>

#define NB 32
#define CCH 64
#define HH 96
#define WWID 96
#define HWP (HH*WWID)   // 9216
#define K7 448

// ws layout (float offsets):
//   t2p : [32][16][64][64] partials        = 2,097,152 floats
//   t5  : [32][64][64]                     =   131,072
//   T8t : [32][64][448] bf16 (kk-major-k') =   458,752 floats of space
//   t6  : [32][9216]                       =   294,912
//   t9  : [32][64]                         =     2,048
#define OFF_T5 2097152
#define OFF_T8 2228224
#define OFF_T6 3145728
#define OFF_T9 3440640

typedef __attribute__((ext_vector_type(8))) short short8;
typedef __attribute__((ext_vector_type(4))) float floatx4;

__device__ __forceinline__ short f2bf(float x) {
    unsigned u = __float_as_uint(x);
    unsigned r = (u + 0x7FFF + ((u >> 16) & 1)) >> 16;  // RNE
    return (short)r;
}

__device__ __forceinline__ int roll_idx(int i) {
    int h = i / WWID;
    int w = i - h * WWID;
    return ((h + HH - 1) % HH) * WWID + ((w + 1) % WWID);
}

// ---------------------------------------------------------------------------
// Kernel A: t2 partials.  t2[n,c,d] = sum_i x[n,c,i] * t1[n,d,i]   (K split 16)
// ---------------------------------------------------------------------------
__global__ __launch_bounds__(256) void k_t2(const float* __restrict__ x,
                                            float* __restrict__ t2p) {
    int blk = blockIdx.x;
    int n = blk >> 4, sl = blk & 15;
    int k0 = sl * (HWP / 16);          // 576 per slice
    __shared__ float ash[32][68];
    __shared__ float bsh[32][68];
    int t = threadIdx.x;
    int c0 = (t >> 4) * 4;
    int d0 = (t & 15) * 4;
    float acc[4][4] = {};
    const float* xa = x + (size_t)n * CCH * HWP;

    for (int kc = 0; kc < 576; kc += 32) {
        __syncthreads();
#pragma unroll
        for (int i = 0; i < 8; i++) {
            int idx = i * 256 + t;
            int c = idx >> 5, kk = idx & 31;
            int gi = k0 + kc + kk;
            ash[kk][c] = xa[c * HWP + gi];
            bsh[kk][c] = xa[c * HWP + roll_idx(gi)];
        }
        __syncthreads();
#pragma unroll
        for (int kk = 0; kk < 32; kk++) {
            float4 va = *(const float4*)&ash[kk][c0];
            float4 vb = *(const float4*)&bsh[kk][d0];
            float av[4] = {va.x, va.y, va.z, va.w};
            float bv[4] = {vb.x, vb.y, vb.z, vb.w};
#pragma unroll
            for (int i = 0; i < 4; i++)
#pragma unroll
                for (int j = 0; j < 4; j++)
                    acc[i][j] = fmaf(av[i], bv[j], acc[i][j]);
        }
    }
    float* o = t2p + (((size_t)n * 16 + sl) * 64 + c0) * 64 + d0;
#pragma unroll
    for (int i = 0; i < 4; i++) {
        float4 v = {acc[i][0], acc[i][1], acc[i][2], acc[i][3]};
        *(float4*)(o + i * 64) = v;
    }
}

// ---------------------------------------------------------------------------
// Kernel B1: t5[n,b,c] = p5[b,c] * (sum_slices t2p) / 96
// ---------------------------------------------------------------------------
__global__ __launch_bounds__(256) void k_t5(const float* __restrict__ t2p,
                                            const float* __restrict__ p5,
                                            float* __restrict__ t5) {
    int idx = blockIdx.x * 256 + threadIdx.x;
    int n = idx >> 12, rc = idx & 4095;
    float s = 0.f;
#pragma unroll
    for (int sl = 0; sl < 16; sl++)
        s += t2p[((size_t)n * 16 + sl) * 4096 + rc];
    t5[idx] = s * p5[rc] * (1.0f / 96.0f);
}

// ---------------------------------------------------------------------------
// Kernel B2: T8t[n][c][kk*64+c7] = bf16( (1/sqrt(448)) * sum_b t5[n,b,c]*p8[b,k] )
// where k = c7*7+kk.  kk-major-k' layout so k_out's A-fragments are contiguous.
// ---------------------------------------------------------------------------
__global__ __launch_bounds__(256) void k_t8(const float* __restrict__ t5,
                                            const float* __restrict__ p8,
                                            short* __restrict__ t8t) {
    int n = blockIdx.y;
    int idx = blockIdx.x * 256 + threadIdx.x;   // [0, 448*64)
    int k = idx >> 6, c = idx & 63;
    const float* t5n = t5 + (size_t)n * 4096;
    float s = 0.f;
#pragma unroll 8
    for (int b = 0; b < 64; b++)
        s += t5n[b * 64 + c] * p8[b * K7 + k];
    int c7 = k / 7, kk = k - c7 * 7;
    t8t[((size_t)n * 64 + c) * K7 + kk * 64 + c7] = f2bf(s * 0.04724555912f);
}

// ---------------------------------------------------------------------------
// Kernel C1: t6[n,h,w] = sum_c p6[c] * dwconv3x3_d2(t1)[n,c,h,w]
// Tap offsets + zero-masks precomputed once; inner loop branch/mod-free.
// ---------------------------------------------------------------------------
__global__ __launch_bounds__(256) void k_t6(const float* __restrict__ x,
                                            const float* __restrict__ w4,
                                            const float* __restrict__ p6,
                                            float* __restrict__ t6) {
    int n = blockIdx.y;
    int pix = blockIdx.x * 256 + threadIdx.x;   // < 9216 (36*256)
    int h = pix / WWID, w = pix - h * WWID;

    int off9[9];
    float m9[9];
#pragma unroll
    for (int i = 0; i < 3; i++) {
        int gh = h + (i - 1) * 2;
        bool vr = (gh >= 0) && (gh < HH);
        int srow = vr ? ((gh + HH - 1) % HH) * WWID : 0;
        float rm = vr ? 1.f : 0.f;
#pragma unroll
        for (int j = 0; j < 3; j++) {
            int gw = w + (j - 1) * 2;
            bool vc = (gw >= 0) && (gw < WWID);
            int scol = vc ? (gw + 1) % WWID : 0;
            off9[i * 3 + j] = srow + scol;
            m9[i * 3 + j] = vc ? rm : 0.f;
        }
    }
    const float* xn = x + (size_t)n * CCH * HWP;
    float acc = 0.f;
    for (int c = 0; c < CCH; c++) {
        const float* xc = xn + c * HWP;
        float pw = p6[c];
        const float* wc = w4 + c * 9;
#pragma unroll
        for (int ij = 0; ij < 9; ij++) {
            float wm = wc[ij] * pw * m9[ij];
            acc = fmaf(wm, xc[off9[ij]], acc);
        }
    }
    t6[(size_t)n * HWP + pix] = acc;
}

// ---------------------------------------------------------------------------
// Kernel C2: t9[n,c] = (1/96) * <conv5x5(t1[c]), t6[n]>
// Whole rolled+padded channel staged in LDS; 4-pixel register blocks.
// ---------------------------------------------------------------------------
__global__ __launch_bounds__(256) void k_t9(const float* __restrict__ x,
                                            const float* __restrict__ w3,
                                            const float* __restrict__ t6,
                                            float* __restrict__ t9) {
    int n = blockIdx.y, c = blockIdx.x;
    __shared__ float xl[100][100];
    __shared__ float red[4];
    int t = threadIdx.x;
    const float* xc = x + ((size_t)n * CCH + c) * HWP;
    const float* t6n = t6 + (size_t)n * HWP;

    // zero borders: rows 0,1,98,99 full (400) + cols 0,1,98,99 of rows 2..97 (384)
    for (int idx = t; idx < 784; idx += 256) {
        if (idx < 400) {
            int r = idx / 100, col = idx - r * 100;
            int row = r < 2 ? r : r + 96;
            xl[row][col] = 0.f;
        } else {
            int rem = idx - 400;
            int h2 = rem >> 2, c4 = rem & 3;
            int col = c4 < 2 ? c4 : c4 + 96;
            xl[2 + h2][col] = 0.f;
        }
    }
    // interior: xl[h+2][w+2] = t1[h][w] = x[(h-1)%96][(w+1)%96]
    for (int idx = t; idx < HWP; idx += 256) {
        int h = idx / WWID, w = idx - h * WWID;
        int sh = (h == 0) ? (HH - 1) : (h - 1);
        int sw = (w == WWID - 1) ? 0 : (w + 1);
        xl[h + 2][w + 2] = xc[sh * WWID + sw];
    }
    float wv[25];
#pragma unroll
    for (int i = 0; i < 25; i++) wv[i] = w3[c * 25 + i];
    __syncthreads();

    float acc = 0.f;
#pragma unroll
    for (int g = 0; g < 9; g++) {
        int idx = g * 256 + t;          // < 2304
        int h = idx / 24, wg = idx - h * 24;
        int w0 = wg * 4;
        float4 tv = *(const float4*)(t6n + h * WWID + w0);
        float conv[4] = {0.f, 0.f, 0.f, 0.f};
#pragma unroll
        for (int kh = 0; kh < 5; kh++) {
            float4 ra = *(const float4*)&xl[h + kh][w0];
            float4 rb = *(const float4*)&xl[h + kh][w0 + 4];
            float r[8] = {ra.x, ra.y, ra.z, ra.w, rb.x, rb.y, rb.z, rb.w};
#pragma unroll
            for (int kw = 0; kw < 5; kw++) {
                float wk = wv[kh * 5 + kw];
                conv[0] = fmaf(wk, r[kw],     conv[0]);
                conv[1] = fmaf(wk, r[kw + 1], conv[1]);
                conv[2] = fmaf(wk, r[kw + 2], conv[2]);
                conv[3] = fmaf(wk, r[kw + 3], conv[3]);
            }
        }
        acc = fmaf(conv[0], tv.x, acc);
        acc = fmaf(conv[1], tv.y, acc);
        acc = fmaf(conv[2], tv.z, acc);
        acc = fmaf(conv[3], tv.w, acc);
    }
#pragma unroll
    for (int off = 32; off > 0; off >>= 1) acc += __shfl_down(acc, off, 64);
    if ((t & 63) == 0) red[t >> 6] = acc;
    __syncthreads();
    if (t == 0)
        t9[n * 64 + c] = (red[0] + red[1] + red[2] + red[3]) * (1.0f / 96.0f);
}

// ---------------------------------------------------------------------------
// Kernel D: bf16 MFMA GEMM.
// out[n,c,s] = t9[n,c] + sum_{k'} T8t[n][c][k'] * T7[k'][s],  k' = kk*64+c7
// T7[k'][s=r*96+w] = xpad[n,c7,h0+r,w+2kk-6]  (bf16, staged channel-minor LDS)
// Block = (h-pair, n).  Wave: 4 m-tiles x 3 s-tiles of 16x16x32 MFMA, K=14 chunks.
// ---------------------------------------------------------------------------
__global__ __launch_bounds__(256) void k_out(const float* __restrict__ x,
                                             const short* __restrict__ t8t,
                                             const float* __restrict__ t9,
                                             float* __restrict__ out) {
    int n = blockIdx.y;
    int h0 = blockIdx.x * 2;
    __shared__ short xsh[2 * 108 * 72];   // [r][iw][c7], iw = w+2kk (pad 6), stride 72
    int t = threadIdx.x;

    // zero halo iw in [0,6) and [102,108)
    for (int idx = t; idx < 2 * 12 * 72; idx += 256) {
        int r = idx / (12 * 72);
        int rem = idx - r * (12 * 72);
        int iwz = rem / 72, c7 = rem - iwz * 72;
        int iw = iwz < 6 ? iwz : iwz + 96;
        xsh[(r * 108 + iw) * 72 + c7] = 0;
    }
    // interior: xsh[r][w+6][c7] = bf16(x[n,c7,h0+r,w])
    const float* xn = x + (size_t)n * CCH * HWP;
    for (int idx = t; idx < 2 * CCH * WWID; idx += 256) {
        int r = idx / (CCH * WWID);
        int rem = idx - r * (CCH * WWID);
        int c7 = rem / WWID, w = rem - c7 * WWID;
        float v = xn[c7 * HWP + (h0 + r) * WWID + w];
        xsh[(r * 108 + w + 6) * 72 + c7] = f2bf(v);
    }
    __syncthreads();

    int lane = t & 63, wv = t >> 6;
    int q = lane >> 4, sl = lane & 15;
    floatx4 acc[4][3] = {};
    const short* A = t8t + (size_t)n * 64 * K7;

    for (int kc = 0; kc < K7; kc += 32) {
        int kk = kc >> 6;
        int c7b = (kc & 63) + q * 8;
        short8 a[4], b[3];
#pragma unroll
        for (int mi = 0; mi < 4; mi++)
            a[mi] = *(const short8*)(A + (mi * 16 + sl) * K7 + kc + q * 8);
#pragma unroll
        for (int sj = 0; sj < 3; sj++) {
            int si = wv * 3 + sj;
            int r = si >= 6 ? 1 : 0;
            int iw = (si - r * 6) * 16 + sl + 2 * kk;
            b[sj] = *(const short8*)&xsh[(r * 108 + iw) * 72 + c7b];
        }
#pragma unroll
        for (int mi = 0; mi < 4; mi++)
#pragma unroll
            for (int sj = 0; sj < 3; sj++)
                acc[mi][sj] = __builtin_amdgcn_mfma_f32_16x16x32_bf16(
                    a[mi], b[sj], acc[mi][sj], 0, 0, 0);
    }

    // epilogue: D col = lane&15 (s), row = q*4+i (c within m-tile)
    const float* t9n = t9 + n * 64;
#pragma unroll
    for (int mi = 0; mi < 4; mi++) {
#pragma unroll
        for (int i = 0; i < 4; i++) {
            int c = mi * 16 + q * 4 + i;
            float tv = t9n[c];
            float* orow = out + ((size_t)n * CCH + c) * HWP;
#pragma unroll
            for (int sj = 0; sj < 3; sj++) {
                int si = wv * 3 + sj;
                int r = si >= 6 ? 1 : 0;
                int w = (si - r * 6) * 16 + sl;
                orow[(h0 + r) * WWID + w] = acc[mi][sj][i] + tv;
            }
        }
    }
}

// ---------------------------------------------------------------------------
extern "C" void kernel_launch(void* const* d_in, const int* in_sizes, int n_in,
                              void* d_out, int out_size, void* d_ws, size_t ws_size,
                              hipStream_t stream) {
    const float* x  = (const float*)d_in[0];
    const float* w3 = (const float*)d_in[1];
    const float* w4 = (const float*)d_in[2];
    const float* p5 = (const float*)d_in[3];
    const float* p6 = (const float*)d_in[4];
    const float* p8 = (const float*)d_in[5];
    float* out = (float*)d_out;
    float* ws  = (float*)d_ws;

    float* t2p = ws;
    float* t5  = ws + OFF_T5;
    short* t8t = (short*)(ws + OFF_T8);
    float* t6  = ws + OFF_T6;
    float* t9  = ws + OFF_T9;

    k_t2<<<512, 256, 0, stream>>>(x, t2p);
    k_t5<<<512, 256, 0, stream>>>(t2p, p5, t5);
    k_t8<<<dim3(112, 32), 256, 0, stream>>>(t5, p8, t8t);
    k_t6<<<dim3(36, 32), 256, 0, stream>>>(x, w4, p6, t6);
    k_t9<<<dim3(64, 32), 256, 0, stream>>>(x, w3, t6, t9);
    k_out<<<dim3(48, 32), 256, 0, stream>>>(x, t8t, t9, out);
}